// Round 13
// baseline (243.548 us; speedup 1.0000x reference)
//
#include <hip/hip_runtime.h>

using uint = unsigned int;
using ushort = unsigned short;

typedef float f32x4 __attribute__((ext_vector_type(4)));
typedef uint u32x4 __attribute__((ext_vector_type(4)));
using short8 = __attribute__((ext_vector_type(8))) short;

// round-to-nearest-even f32 -> bf16 (as ushort)
__device__ __forceinline__ ushort f2bf(float f) {
  uint u = __float_as_uint(f);
  u += 0x7fffu + ((u >> 16) & 1u);
  return (ushort)(u >> 16);
}

// async global->LDS, 16B per lane; LDS dest must be linear (wave base + lane*16)
#define GLOAD_LDS16(gptr, lptr)                                                   \
  __builtin_amdgcn_global_load_lds(                                               \
      (const __attribute__((address_space(1))) void*)(gptr),                      \
      (__attribute__((address_space(3))) void*)(lptr), 16, 0, 0)

// --------------------------------------------- merged cast kernel (5 segments)
__global__ void cast_all_bf16(const float* __restrict__ X,
                              const float* __restrict__ Wq,
                              const float* __restrict__ Wk,
                              const float* __restrict__ Wv,
                              const float* __restrict__ Wo,
                              ushort* __restrict__ dst /* Xb base */) {
  const int e0 = 2097152;            // X  (8M floats, float4 units)
  const int e1 = e0 + 1048576;       // Wq
  const int e2 = e1 + 262144;        // Wk
  const int e3 = e2 + 262144;        // Wv
  const int e4 = e3 + 1048576;       // Wo
  const int stride = gridDim.x * blockDim.x;
  for (int i = blockIdx.x * blockDim.x + threadIdx.x; i < e4; i += stride) {
    const float* src;
    int j;
    if (i < e0)      { src = X;  j = i; }
    else if (i < e1) { src = Wq; j = i - e0; }
    else if (i < e2) { src = Wk; j = i - e1; }
    else if (i < e3) { src = Wv; j = i - e2; }
    else             { src = Wo; j = i - e3; }
    float4 v = reinterpret_cast<const float4*>(src)[j];
    ushort4 o;
    o.x = f2bf(v.x); o.y = f2bf(v.y); o.z = f2bf(v.z); o.w = f2bf(v.w);
    reinterpret_cast<ushort4*>(dst)[i] = o;
  }
}

// ------------------------------------------------- 128x128 BK=32 GEMM mainloop
__device__ __forceinline__ void gemm128_mainloop(const ushort* __restrict__ A,
                                                 const ushort* __restrict__ W,
                                                 int K, ushort* As, ushort* Bs,
                                                 f32x4 (&acc)[4][4]) {
  const int tid = threadIdx.x;
  const int lane = tid & 63;
  const int wr = (tid >> 7) & 1;
  const int wc = (tid >> 6) & 1;
  const char* aP = (const char*)(A + (size_t)(tid >> 2) * K) + (tid & 3) * 16;
  const char* bP = (const char*)(W + (size_t)(tid >> 2) * K) + (tid & 3) * 16;
  const size_t rowHop = (size_t)64 * K * 2;
  ushort* aL0 = As + tid * 8;
  ushort* aL1 = As + 2048 + tid * 8;
  ushort* bL0 = Bs + tid * 8;
  ushort* bL1 = Bs + 2048 + tid * 8;
  const int ar = lane & 15;
  const int ak = (lane >> 4) * 8;

  for (int k0 = 0; k0 < K; k0 += 32) {
    GLOAD_LDS16(aP, aL0);
    GLOAD_LDS16(aP + rowHop, aL1);
    GLOAD_LDS16(bP, bL0);
    GLOAD_LDS16(bP + rowHop, bL1);
    aP += 64; bP += 64;
    __syncthreads();
    short8 af[4], bf[4];
#pragma unroll
    for (int i = 0; i < 4; ++i)
      af[i] = *reinterpret_cast<const short8*>(&As[(wr * 64 + i * 16 + ar) * 32 + ak]);
#pragma unroll
    for (int i = 0; i < 4; ++i)
      bf[i] = *reinterpret_cast<const short8*>(&Bs[(wc * 64 + i * 16 + ar) * 32 + ak]);
#pragma unroll
    for (int mi = 0; mi < 4; ++mi)
#pragma unroll
      for (int ni = 0; ni < 4; ++ni)
        acc[mi][ni] = __builtin_amdgcn_mfma_f32_16x16x32_bf16(af[mi], bf[ni],
                                                              acc[mi][ni], 0, 0, 0);
    __syncthreads();
  }
}

// -------------------------------------------------------------- fused QKV GEMM
// V output in 16x16-MFMA B-frag order with kv-permutation sigma shared with the
// attention P-fragment:  sigma_ks(8*gp + j) = 32*ks + 16*(j>>2) + 4*gp + (j&3).
// For attn lane l (gp=l>>4, dl=l&15), chunk ks, d-tile dt, elem j:
//   B[k_virtual=8*gp+j][d=16*dt+dl] = V[64*t + sigma_ks(8*gp+j)][d]
//   flat: ((b*4+g)*32 + t)*8192 + (ks*8+dt)*512 + l*8 + j
__global__ __launch_bounds__(256) void qkv_gemm(
    const ushort* __restrict__ Xb, const ushort* __restrict__ Wq,
    const ushort* __restrict__ Wk, const ushort* __restrict__ Wv,
    const float* __restrict__ bq, const float* __restrict__ bk,
    const float* __restrict__ bv, ushort* __restrict__ Qb,
    ushort* __restrict__ Kb, ushort* __restrict__ Vf) {
  __shared__ ushort As[128 * 32], Bs[128 * 32];
  const int bx = blockIdx.x, by = blockIdx.y;
  const ushort* W; const float* bias; ushort* out;
  int n0, mode, ldo;
  if (bx < 16)      { W = Wq; bias = bq; out = Qb; n0 = bx * 128;        mode = 0; ldo = 2048; }
  else if (bx < 20) { W = Wk; bias = bk; out = Kb; n0 = (bx - 16) * 128; mode = 0; ldo = 512; }
  else              { W = Wv; bias = bv; out = Vf; n0 = (bx - 20) * 128; mode = 1; ldo = 0; }

  f32x4 acc[4][4] = {};
  gemm128_mainloop(Xb + (size_t)by * 128 * 2048, W + (size_t)n0 * 2048, 2048, As, Bs, acc);

  const int lane = threadIdx.x & 63;
  const int wr = (threadIdx.x >> 7) & 1, wc = (threadIdx.x >> 6) & 1;
  const int r0 = by * 128 + wr * 64 + ((lane >> 4) * 4);
  const int c0 = wc * 64 + (lane & 15);
#pragma unroll
  for (int mi = 0; mi < 4; ++mi)
#pragma unroll
    for (int ni = 0; ni < 4; ++ni) {
      const int col = c0 + ni * 16;
      const float bb = bias[n0 + col];
#pragma unroll
      for (int j = 0; j < 4; ++j) {
        const int row = r0 + mi * 16 + j;
        const float v = acc[mi][ni][j] + bb;
        if (mode == 0) {
          out[(size_t)row * ldo + n0 + col] = f2bf(v);
        } else {  // V sigma-permuted 16x16-frag layout (see header comment)
          const int b2 = row >> 11, s = row & 2047;
          const int vc = n0 + col;               // 0..511
          const int g2 = vc >> 7, d = vc & 127;
          const int t2 = s >> 6;
          const int ks = (s >> 5) & 1;
          const int jhi = (s >> 4) & 1;          // j>>2
          const int gp2 = (s >> 2) & 3;
          const int j2 = jhi * 4 + (s & 3);
          const int dt = d >> 4, dl = d & 15;
          const int l = gp2 * 16 + dl;
          out[(size_t)((b2 * 4 + g2) * 32 + t2) * 8192 +
              (ks * 8 + dt) * 512 + l * 8 + j2] = f2bf(v);
        }
      }
    }
}

// ------------------------------------------------------------ out-projection
__global__ __launch_bounds__(256) void out_gemm(const ushort* __restrict__ Mid,
                                                const ushort* __restrict__ Wo,
                                                const float* __restrict__ bo,
                                                float* __restrict__ Out) {
  __shared__ ushort As[128 * 32], Bs[128 * 32];
  const int bx = blockIdx.x, by = blockIdx.y;
  f32x4 acc[4][4] = {};
  gemm128_mainloop(Mid + (size_t)by * 128 * 2048, Wo + (size_t)bx * 128 * 2048,
                   2048, As, Bs, acc);
  const int lane = threadIdx.x & 63;
  const int wr = (threadIdx.x >> 7) & 1, wc = (threadIdx.x >> 6) & 1;
  const int r0 = by * 128 + wr * 64 + ((lane >> 4) * 4);
  const int c0 = bx * 128 + wc * 64 + (lane & 15);
#pragma unroll
  for (int mi = 0; mi < 4; ++mi)
#pragma unroll
    for (int ni = 0; ni < 4; ++ni) {
      const int col = c0 + ni * 16;
      const float bb = bo[col];
#pragma unroll
      for (int j = 0; j < 4; ++j)
        Out[(size_t)(r0 + mi * 16 + j) * 2048 + col] = acc[mi][ni][j] + bb;
    }
}

// ------------------------------------------------------------ flash attention
// q=16/wave on 16x16x32 MFMA, sigma-permuted PV (NO cross-lane ops in loop).
// S^T = K Q^T: lane (lq=l&15, gp=l>>4) holds st[kvt][r] = S[kv=16kvt+4gp+r][q=lq].
// After cvt_pk, pa[ks] = {w[2ks][0], w[2ks][1], w[2ks+1][0], w[2ks+1][1]} IS the
// PV A-fragment under sigma; V was written sigma-permuted by qkv_gemm.
// Fixed-max softmax; denominator l via mfma(P, ones) (4 AGPRs).
// Block = 4 waves x 16q = 64q; grid (32,16,2)=1024 blocks, LDS 32KB.
// Register-lean V staging (consume-A-then-issue-B) targets <=128 unified regs
// => 4 waves/SIMD. No forced min-waves (R10 lesson).
__global__ __launch_bounds__(256) void attn_fwd(const ushort* __restrict__ Q,
                                                const ushort* __restrict__ Kb,
                                                const ushort* __restrict__ Vf,
                                                ushort* __restrict__ Mid) {
  __shared__ ushort Ks[2][64 * 128];

  const int tid = threadIdx.x, lane = tid & 63, wave = tid >> 6;
  const int h = blockIdx.y, b = blockIdx.z, g = h >> 2;
  const int q0w = blockIdx.x * 64 + wave * 16;
  const int lq = lane & 15, gp = lane >> 4;

  const char* kbase = (const char*)Kb + ((size_t)b * 2048 * 512 + g * 128) * 2;
  int kRow[4], kOff[4];
#pragma unroll
  for (int i = 0; i < 4; ++i) {
    const int off = (i * 256 + tid) * 16;
    const int r = off >> 8, c = off & 255;       // K rows: 256B = 16 slots
    kRow[i] = r; kOff[i] = c ^ ((r & 15) << 4);  // 16-slot swizzle
  }

  // stage K tile 0
#pragma unroll
  for (int i = 0; i < 4; ++i)
    GLOAD_LDS16(kbase + (size_t)kRow[i] * 1024 + kOff[i],
                (char*)Ks[0] + (i * 256 + tid) * 16);

  // V fragment base for this lane
  const ushort* vfb = Vf + (size_t)(b * 4 + g) * 262144 + lane * 8;

  // Q B-frags: Q[q0w+lq][32c + gp*8 + j]
  short8 qf[4];
  {
    const ushort* qp = Q + (size_t)(b * 2048 + q0w + lq) * 2048 + h * 128 + gp * 8;
#pragma unroll
    for (int c = 0; c < 4; ++c)
      qf[c] = *reinterpret_cast<const short8*>(qp + c * 32);
  }

  short8 onesf;
#pragma unroll
  for (int i = 0; i < 8; ++i) onesf[i] = (short)0x3F80;

  f32x4 o[8] = {};
  f32x4 ol = {};
  const float sc2 = 0.08838834764831843f * 1.44269504088896340736f;  // /sqrt(hd)*log2e
  const float FM = 8.0f;  // fixed softmax shift (log2 domain)

  __syncthreads();

  const int ksw = lq << 4;

  for (int t = 0; t < 32; ++t) {
    const int cur = t & 1;
    const ushort* vt = vfb + t * 8192;

    // ---- V chunk A (ks=0, all 8 d-tiles) issued early
    short8 vrA0[4], vrA1[4];
#pragma unroll
    for (int u = 0; u < 4; ++u)
      vrA0[u] = *reinterpret_cast<const short8*>(vt + u * 512);
#pragma unroll
    for (int u = 0; u < 4; ++u)
      vrA1[u] = *reinterpret_cast<const short8*>(vt + (4 + u) * 512);

    // ---- K prefetch for tile t+1
    if (t < 31) {
      const int kv0 = (t + 1) * 64;
#pragma unroll
      for (int i = 0; i < 4; ++i)
        GLOAD_LDS16(kbase + (size_t)(kv0 + kRow[i]) * 1024 + kOff[i],
                    (char*)Ks[cur ^ 1] + (i * 256 + tid) * 16);
    }

    // ---- S^T = K Q^T : st[kvt][r] = S[kv=16*kvt+4*gp+r][q=lq]
    const char* ksb = (const char*)Ks[cur];
    f32x4 st[4] = {};
    __builtin_amdgcn_s_setprio(1);
#pragma unroll
    for (int c = 0; c < 4; ++c) {
      const int cb = (c * 64 + gp * 16) ^ ksw;
#pragma unroll
      for (int kvt = 0; kvt < 4; ++kvt) {
        short8 kf = *reinterpret_cast<const short8*>(ksb + (kvt * 16 + lq) * 256 + cb);
        st[kvt] = __builtin_amdgcn_mfma_f32_16x16x32_bf16(kf, qf[c], st[kvt], 0, 0, 0);
      }
    }
    __builtin_amdgcn_s_setprio(0);

    // ---- fixed-max exp (per-register, no reduction dependency)
#pragma unroll
    for (int kvt = 0; kvt < 4; ++kvt)
#pragma unroll
      for (int r = 0; r < 4; ++r)
        st[kvt][r] = exp2f(fmaf(st[kvt][r], sc2, -FM));

    // ---- pack: w[kvt][p] = bf16x2(st[kvt][2p], st[kvt][2p+1])
    uint w[4][2];
#pragma unroll
    for (int kvt = 0; kvt < 4; ++kvt) {
      asm("v_cvt_pk_bf16_f32 %0, %1, %2" : "=v"(w[kvt][0]) : "v"(st[kvt][0]), "v"(st[kvt][1]));
      asm("v_cvt_pk_bf16_f32 %0, %1, %2" : "=v"(w[kvt][1]) : "v"(st[kvt][2]), "v"(st[kvt][3]));
    }
    // pa[ks] = lane-local words; sigma ordering matches V layout (no shuffles)
    short8 pa[2];
    {
      u32x4 wv0 = {w[0][0], w[0][1], w[1][0], w[1][1]};
      u32x4 wv1 = {w[2][0], w[2][1], w[3][0], w[3][1]};
      pa[0] = __builtin_bit_cast(short8, wv0);
      pa[1] = __builtin_bit_cast(short8, wv1);
    }

    // ---- O += P V ; l += P 1  (consume A-chunks, then issue+consume B-chunks)
    __builtin_amdgcn_s_setprio(1);
#pragma unroll
    for (int dt = 0; dt < 4; ++dt)
      o[dt] = __builtin_amdgcn_mfma_f32_16x16x32_bf16(pa[0], vrA0[dt], o[dt], 0, 0, 0);
    ol = __builtin_amdgcn_mfma_f32_16x16x32_bf16(pa[0], onesf, ol, 0, 0, 0);
    __builtin_amdgcn_s_setprio(0);

    short8 vrB0[4];
#pragma unroll
    for (int u = 0; u < 4; ++u)
      vrB0[u] = *reinterpret_cast<const short8*>(vt + (8 + u) * 512);

    __builtin_amdgcn_s_setprio(1);
#pragma unroll
    for (int dt = 0; dt < 4; ++dt)
      o[4 + dt] = __builtin_amdgcn_mfma_f32_16x16x32_bf16(pa[0], vrA1[dt], o[4 + dt], 0, 0, 0);
    __builtin_amdgcn_s_setprio(0);

    short8 vrB1[4];
#pragma unroll
    for (int u = 0; u < 4; ++u)
      vrB1[u] = *reinterpret_cast<const short8*>(vt + (12 + u) * 512);

    __builtin_amdgcn_s_setprio(1);
#pragma unroll
    for (int dt = 0; dt < 4; ++dt)
      o[dt] = __builtin_amdgcn_mfma_f32_16x16x32_bf16(pa[1], vrB0[dt], o[dt], 0, 0, 0);
    ol = __builtin_amdgcn_mfma_f32_16x16x32_bf16(pa[1], onesf, ol, 0, 0, 0);
#pragma unroll
    for (int dt = 0; dt < 4; ++dt)
      o[4 + dt] = __builtin_amdgcn_mfma_f32_16x16x32_bf16(pa[1], vrB1[dt], o[4 + dt], 0, 0, 0);
    __builtin_amdgcn_s_setprio(0);

    __syncthreads();  // K buffer swap safety
  }

  // ---- epilogue: C row = gp*4 + r (q), col = lq (d within 16-tile)
#pragma unroll
  for (int r = 0; r < 4; ++r) {
    const int q = q0w + gp * 4 + r;
    const float lv = 1.f / ol[r];
    ushort* mp = Mid + (size_t)(b * 2048 + q) * 2048 + h * 128 + lq;
#pragma unroll
    for (int dt = 0; dt < 8; ++dt)
      mp[dt * 16] = f2bf(o[dt][r] * lv);
  }
}

// ------------------------------------------------------------------- launcher
extern "C" void kernel_launch(void* const* d_in, const int* in_sizes, int n_in,
                              void* d_out, int out_size, void* d_ws, size_t ws_size,
                              hipStream_t stream) {
  const float* X  = (const float*)d_in[0];
  const float* Wq = (const float*)d_in[1];
  const float* bq = (const float*)d_in[2];
  const float* Wk = (const float*)d_in[3];
  const float* bk = (const float*)d_in[4];
  const float* Wv = (const float*)d_in[5];
  const float* bv = (const float*)d_in[6];
  const float* Wo = (const float*)d_in[7];
  const float* bo = (const float*)d_in[8];
  float* Out = (float*)d_out;

  // ws layout (bytes); Xb..Wob contiguous = merged cast destination
  char* ws = (char*)d_ws;
  ushort* Xb   = (ushort*)(ws);              // 16 MB, [B*S,2048], cast dst base
  ushort* Wqb  = (ushort*)(ws + 16777216);   //  8 MB
  ushort* Wkb  = (ushort*)(ws + 25165824);   //  2 MB
  ushort* Wvb  = (ushort*)(ws + 27262976);   //  2 MB
  ushort* Wob  = (ushort*)(ws + 29360128);   //  8 MB
  ushort* Qb   = (ushort*)(ws + 37748736);   // 16 MB, [B*S,2048]
  ushort* Kbuf = (ushort*)(ws + 54525952);   //  4 MB, [B*S,512]
  ushort* Vfb  = (ushort*)(ws + 58720256);   //  4 MB, V in sigma 16x16-frag order
  ushort* Midb = (ushort*)(ws + 62914560);   // 16 MB, [B*S,2048]

  cast_all_bf16<<<dim3(2048), dim3(256), 0, stream>>>(X, Wq, Wk, Wv, Wo, Xb);

  qkv_gemm<<<dim3(24, 32), 256, 0, stream>>>(Xb, Wqb, Wkb, Wvb, bq, bk, bv,
                                             Qb, Kbuf, Vfb);
  attn_fwd<<<dim3(32, 16, 2), 256, 0, stream>>>(Qb, Kbuf, Vfb, Midb);
  out_gemm<<<dim3(16, 32), 256, 0, stream>>>(Midb, Wob, bo, Out);
}